// Round 5
// baseline (453.146 us; speedup 1.0000x reference)
//
#include <hip/hip_runtime.h>
#include <hip/hip_bf16.h>

#define HD   64
#define SEQ  2048
#define NB   256
#define TWOH 128
#define NCH  32   // SEQ / 64

typedef float v4f __attribute__((ext_vector_type(4)));

// ws float layout:
// [0,4096)      k_tab  (normalized k per token)
// [4096,8192)   v_tab
// [8192,12288)  q_tab
// [12288,12352) thr2   ((0.4*||v_t||)^2)
// [12352]       bf16 input flag
// [12416,16512) G = K K^T  (Gram of normalized keys)

#define WS_V    4096
#define WS_Q    8192
#define WS_THR  12288
#define WS_FLAG 12352
#define WS_G    12416

// ---- DPP wave-total: sum across 64 lanes, broadcast via lane 63 ----
template <int CTRL>
__device__ __forceinline__ float dpp_add(float x) {
    int y = __builtin_amdgcn_update_dpp(0, __builtin_bit_cast(int, x),
                                        CTRL, 0xF, 0xF, true);
    return x + __builtin_bit_cast(float, y);
}

__device__ __forceinline__ float wave_total(float x) {
    x = dpp_add<0x111>(x);   // row_shr:1
    x = dpp_add<0x112>(x);   // row_shr:2
    x = dpp_add<0x114>(x);   // row_shr:4
    x = dpp_add<0x118>(x);   // row_shr:8
    x = dpp_add<0x142>(x);   // row_bcast:15
    x = dpp_add<0x143>(x);   // row_bcast:31 -> lane 63 has full sum
    return __builtin_bit_cast(float,
        __builtin_amdgcn_readlane(__builtin_bit_cast(int, x), 63));
}

__device__ __forceinline__ float bcastf(float v, int l) {
    return __builtin_bit_cast(float,
        __builtin_amdgcn_readlane(__builtin_bit_cast(int, v), l));
}

// f32 data read as bf16 at even 16-bit halves -> mantissa bits land in the
// exponent field -> huge/NaN values. True bf16 inputs are ~0.05-scale.
__device__ __forceinline__ bool detect_bf16(const void* embed) {
    const unsigned short* u = (const unsigned short*)embed;
    int bad = 0;
    for (int i = 2 * threadIdx.x; i < 4096; i += 128) {
        float v = __uint_as_float(((unsigned int)u[i]) << 16);
        if (!(fabsf(v) < 1e4f)) bad = 1;
    }
    return !__any(bad);
}

template <bool BF>
__device__ __forceinline__ float ldf(const void* p, int i) {
    if (BF) return __bfloat162float(((const __hip_bfloat16*)p)[i]);
    return ((const float*)p)[i];
}

template <bool BF>
__device__ void precompute_body(const void* embed, const void* w1, const void* b1,
                                const void* w2, const void* b2, const void* ln_g,
                                const void* ln_b, const void* wk, const void* wv,
                                const void* wq, float* __restrict__ ws) {
    const int t = blockIdx.x, d = threadIdx.x;   // block = token, lanes = dims
    __shared__ float sh_h[HD];
    __shared__ float sh_u[TWOH];

    float h = ldf<BF>(embed, t * HD + d);
    sh_h[d] = h;
    __syncthreads();

    float a0 = 0.f, a1 = 0.f, a2 = 0.f, a3 = 0.f;
    #pragma unroll 16
    for (int j = 0; j < HD; j += 2) {
        float h0 = sh_h[j], h1 = sh_h[j + 1];
        a0 = fmaf(h0, ldf<BF>(w1, j * TWOH + d), a0);
        a1 = fmaf(h0, ldf<BF>(w1, j * TWOH + d + HD), a1);
        a2 = fmaf(h1, ldf<BF>(w1, (j + 1) * TWOH + d), a2);
        a3 = fmaf(h1, ldf<BF>(w1, (j + 1) * TWOH + d + HD), a3);
    }
    float u0 = fmaxf(a0 + a2 + ldf<BF>(b1, d), 0.f);
    float u1 = fmaxf(a1 + a3 + ldf<BF>(b1, d + HD), 0.f);
    sh_u[d] = u0;
    sh_u[d + HD] = u1;
    __syncthreads();

    float f0 = 0.f, f1 = 0.f, f2 = 0.f, f3 = 0.f;
    #pragma unroll 16
    for (int e = 0; e < TWOH; e += 4) {
        f0 = fmaf(sh_u[e + 0], ldf<BF>(w2, (e + 0) * HD + d), f0);
        f1 = fmaf(sh_u[e + 1], ldf<BF>(w2, (e + 1) * HD + d), f1);
        f2 = fmaf(sh_u[e + 2], ldf<BF>(w2, (e + 2) * HD + d), f2);
        f3 = fmaf(sh_u[e + 3], ldf<BF>(w2, (e + 3) * HD + d), f3);
    }
    float y = h + (f0 + f1) + (f2 + f3) + ldf<BF>(b2, d);

    float mu  = wave_total(y) * 0.015625f;
    float dv  = y - mu;
    float var = wave_total(dv * dv) * 0.015625f;
    float hn  = fmaf(dv * (1.f / sqrtf(var + 1e-5f)), ldf<BF>(ln_g, d),
                     ldf<BF>(ln_b, d));

    __syncthreads();
    sh_h[d] = hn;
    __syncthreads();

    float k0 = 0.f, k1 = 0.f, v0 = 0.f, v1 = 0.f, q0 = 0.f, q1 = 0.f;
    #pragma unroll 16
    for (int j = 0; j < HD; j += 2) {
        float h0 = sh_h[j], h1 = sh_h[j + 1];
        k0 = fmaf(h0, ldf<BF>(wk, j * HD + d), k0);
        v0 = fmaf(h0, ldf<BF>(wv, j * HD + d), v0);
        q0 = fmaf(h0, ldf<BF>(wq, j * HD + d), q0);
        k1 = fmaf(h1, ldf<BF>(wk, (j + 1) * HD + d), k1);
        v1 = fmaf(h1, ldf<BF>(wv, (j + 1) * HD + d), v1);
        q1 = fmaf(h1, ldf<BF>(wq, (j + 1) * HD + d), q1);
    }
    float k = k0 + k1, v = v0 + v1, q = q0 + q1;
    float nk = sqrtf(wave_total(k * k));
    k /= fmaxf(nk, 1e-12f);
    float nv2 = wave_total(v * v);

    ws[t * HD + d]        = k;
    ws[WS_V + t * HD + d] = v;
    ws[WS_Q + t * HD + d] = q;
    if (d == 0) ws[WS_THR + t] = 0.16f * nv2;   // (0.4*||v||)^2
    if (t == 0 && d == 0) ws[WS_FLAG] = BF ? 1.f : 0.f;
}

__global__ __launch_bounds__(64) void precompute_kernel(
    const void* embed, const void* w1, const void* b1, const void* w2,
    const void* b2, const void* ln_g, const void* ln_b, const void* wk,
    const void* wv, const void* wq, float* __restrict__ ws) {
    if (detect_bf16(embed))
        precompute_body<true>(embed, w1, b1, w2, b2, ln_g, ln_b, wk, wv, wq, ws);
    else
        precompute_body<false>(embed, w1, b1, w2, b2, ln_g, ln_b, wk, wv, wq, ws);
}

// G[t][u] = k_t . k_u  (block t, lane u).
__global__ __launch_bounds__(64) void gram_kernel(float* __restrict__ ws) {
    const int t = blockIdx.x, u = threadIdx.x;
    __shared__ float kt[HD];
    kt[u] = ws[t * HD + u];
    __syncthreads();
    const float* kr = ws + u * HD;
    float g0 = 0.f, g1 = 0.f, g2 = 0.f, g3 = 0.f;
    #pragma unroll
    for (int j = 0; j < HD; j += 4) {
        float4 kv = *(const float4*)&kr[j];
        g0 = fmaf(kt[j + 0], kv.x, g0);
        g1 = fmaf(kt[j + 1], kv.y, g1);
        g2 = fmaf(kt[j + 2], kv.z, g2);
        g3 = fmaf(kt[j + 3], kv.w, g3);
    }
    ws[WS_G + t * HD + u] = (g0 + g1) + (g2 + g3);
}

// One wave per batch. Lane t owns token t's residual dv_t (16 v4f regs).
// nd2 (lane-local) -> fireset = ballot(nd2 > thr2) covers all 64 tokens.
// Fire on t: lane t exports its dv row to LDS; explicit lgkmcnt(0) barrier
// (compiler "memory" clobber prevents store->load forwarding across the
// divergent store — R4's blowup); all lanes read it back uniform-address
// (LDS broadcast), then packed-f32 FMAs:
//   dv_u -= G[t][u] * delta
//   R    += cq_t * delta   (cq_t = k_t . q; q known upfront from last token)
//   nd2  = ||dv_u||^2
// Readout: out = relu(R) @ wo + bo   (R is bitwise-identical on all lanes).
__global__ __launch_bounds__(64, 1) void scan_kernel(
    const int* __restrict__ x, const float* __restrict__ ws,
    const void* __restrict__ wo, const void* __restrict__ bo,
    void* __restrict__ out) {
    const int b = blockIdx.x, lane = threadIdx.x;
    __shared__ __align__(16) float g_lds[4096];
    __shared__ __align__(16) float xfer[HD];
    __shared__ int tok_lds[SEQ];

    // stage G + token stream (coalesced)
    #pragma unroll
    for (int i = 0; i < 16; ++i) {
        int o = i * 256 + lane * 4;
        *(float4*)&g_lds[o] = *(const float4*)&ws[WS_G + o];
    }
    const int* xr = x + b * SEQ;
    #pragma unroll
    for (int c = 0; c < NCH; ++c) tok_lds[c * 64 + lane] = xr[c * 64 + lane];

    const float thr2 = ws[WS_THR + lane];
    const bool  bf   = ws[WS_FLAG] != 0.f;

    // cq_lane = k_lane . q_{last token}
    const int tl = xr[SEQ - 1];
    const float* qrow = ws + WS_Q + tl * HD;
    const float* krow = ws + lane * HD;
    float c0 = 0.f, c1 = 0.f, c2 = 0.f, c3 = 0.f;
    #pragma unroll
    for (int j = 0; j < HD; j += 4) {
        float4 kv = *(const float4*)&krow[j];
        c0 = fmaf(qrow[j + 0], kv.x, c0);
        c1 = fmaf(qrow[j + 1], kv.y, c1);
        c2 = fmaf(qrow[j + 2], kv.z, c2);
        c3 = fmaf(qrow[j + 3], kv.w, c3);
    }
    const float cq = (c0 + c1) + (c2 + c3);

    // dv = v_lane (M = 0); R = 0; nd2 = ||dv||^2
    v4f dv[16], R[16];
    const float* vr = ws + WS_V + lane * HD;
    v4f acc = {0.f, 0.f, 0.f, 0.f};
    #pragma unroll
    for (int i = 0; i < 16; ++i) {
        float4 vv = *(const float4*)&vr[i * 4];
        dv[i] = (v4f){vv.x, vv.y, vv.z, vv.w};
        R[i]  = (v4f){0.f, 0.f, 0.f, 0.f};
        acc   = __builtin_elementwise_fma(dv[i], dv[i], acc);
    }
    float nd2 = (acc.x + acc.y) + (acc.z + acc.w);
    __syncthreads();
    unsigned long long fireset = __ballot(nd2 > thr2);

    int chunk = tok_lds[lane];
    #pragma unroll 1
    for (int c = 0; c < NCH; ++c) {
        int nxt = 0;
        if (c + 1 < NCH) nxt = tok_lds[(c + 1) * 64 + lane];
        unsigned long long pend = __ballot((int)((fireset >> chunk) & 1ull));
        while (pend) {
            const int s = __builtin_ctzll(pend);
            const int t = __builtin_amdgcn_readlane(chunk, s);
            const float g   = g_lds[t * HD + lane];        // G[t][lane]
            const float cqt = bcastf(cq, t);
            if (lane == t) {                               // export delta row
                #pragma unroll
                for (int i = 0; i < 16; ++i)
                    *(v4f*)&xfer[i * 4] = dv[i];
            }
            // HW: per-wave DS in-order + lgkmcnt(0). Compiler: "memory"
            // clobber blocks store->load forwarding / reordering (R4 bug).
            asm volatile("s_waitcnt lgkmcnt(0)" ::: "memory");
            const v4f gs  = {-g, -g, -g, -g};
            const v4f cqs = {cqt, cqt, cqt, cqt};
            v4f q4 = {0.f, 0.f, 0.f, 0.f};
            #pragma unroll
            for (int i = 0; i < 16; ++i) {
                const v4f sv = *(const v4f*)&xfer[i * 4];   // uniform: broadcast
                dv[i] = __builtin_elementwise_fma(gs, sv, dv[i]);
                R[i]  = __builtin_elementwise_fma(cqs, sv, R[i]);
                q4    = __builtin_elementwise_fma(dv[i], dv[i], q4);
            }
            nd2 = (q4.x + q4.y) + (q4.z + q4.w);
            fireset = __ballot(nd2 > thr2);
            const unsigned long long above =
                (s >= 63) ? 0ull : (~0ull << (s + 1));
            pend = __ballot((int)((fireset >> chunk) & 1ull)) & above;
        }
        chunk = nxt;
    }

    // out[b][c] = sum_j relu(R[j]) * wo[j][c] + bo[c]   (lane = c; R uniform)
    if (bf) {
        float acc2 = __bfloat162float(((const __hip_bfloat16*)bo)[lane]);
        #pragma unroll
        for (int i = 0; i < 16; ++i) {
            #pragma unroll
            for (int e = 0; e < 4; ++e) {
                float rj = fmaxf(R[i][e], 0.f);
                acc2 = fmaf(rj,
                    __bfloat162float(((const __hip_bfloat16*)wo)[(i * 4 + e) * HD + lane]),
                    acc2);
            }
        }
        ((__hip_bfloat16*)out)[b * HD + lane] = __float2bfloat16(acc2);
    } else {
        float acc2 = ((const float*)bo)[lane];
        #pragma unroll
        for (int i = 0; i < 16; ++i) {
            #pragma unroll
            for (int e = 0; e < 4; ++e) {
                float rj = fmaxf(R[i][e], 0.f);
                acc2 = fmaf(rj, ((const float*)wo)[(i * 4 + e) * HD + lane], acc2);
            }
        }
        ((float*)out)[b * HD + lane] = acc2;
    }
}

extern "C" void kernel_launch(void* const* d_in, const int* in_sizes, int n_in,
                              void* d_out, int out_size, void* d_ws, size_t ws_size,
                              hipStream_t stream) {
    const int* x      = (const int*)d_in[0];
    const void* embed = d_in[1];
    const void* w1    = d_in[2];
    const void* b1    = d_in[3];
    const void* w2    = d_in[4];
    const void* b2    = d_in[5];
    const void* ln_g  = d_in[6];
    const void* ln_b  = d_in[7];
    const void* wk    = d_in[8];
    const void* wv    = d_in[9];
    const void* wq    = d_in[10];
    const void* wo    = d_in[11];
    const void* bo    = d_in[12];
    float* ws = (float*)d_ws;

    precompute_kernel<<<64, 64, 0, stream>>>(embed, w1, b1, w2, b2, ln_g, ln_b,
                                             wk, wv, wq, ws);
    gram_kernel<<<64, 64, 0, stream>>>(ws);
    scan_kernel<<<NB, 64, 0, stream>>>(x, ws, wo, bo, d_out);
}